// Round 22
// baseline (213.657 us; speedup 1.0000x reference)
//
#include <hip/hip_runtime.h>
#include <hip/hip_cooperative_groups.h>
#include <stdint.h>

namespace cg = cooperative_groups;

// Problem constants (fixed by setup_inputs): B=32, N=512, D=512
#define BATCH 32
#define NDIM 512
#define DDIM 512
#define XELEMS (BATCH * NDIM * DDIM)   // 8388608

typedef _Float16 f16x8 __attribute__((ext_vector_type(8)));
typedef float f32x4 __attribute__((ext_vector_type(4)));

__device__ __forceinline__ f16x8 cvt8(float4 u0, float4 u1) {
    f16x8 r;
    r[0] = (_Float16)u0.x; r[1] = (_Float16)u0.y;
    r[2] = (_Float16)u0.z; r[3] = (_Float16)u0.w;
    r[4] = (_Float16)u1.x; r[5] = (_Float16)u1.y;
    r[6] = (_Float16)u1.z; r[7] = (_Float16)u1.w;
    return r;
}

// --- async global -> LDS, 16 bytes per lane (global_load_lds_dwordx4) ---
__device__ __forceinline__ void gl_lds16(const _Float16* g, _Float16* l) {
    __builtin_amdgcn_global_load_lds(
        (const __attribute__((address_space(1))) unsigned int*)(g),
        (__attribute__((address_space(3))) unsigned int*)(l),
        16, 0, 0);
}

// counted vmcnt wait + scheduling fence (rule 18)
#define WAITVM(N) do { asm volatile("s_waitcnt vmcnt(" #N ")" ::: "memory"); \
                       __builtin_amdgcn_sched_barrier(0); } while (0)

// ===================================================================================
// [R21 — SINGLE COOPERATIVE DISPATCH: prep + grid.sync() + fused. Ledger: R14 family
//  measured 105.6/105.8/106.4/107.8 (noise ±2 µs); layout was the only kernel-side
//  win; machinery (R15), occupancy (R17), depth (R19) all proven non-binding. The
//  last untested lever is the DISPATCH BOUNDARY: prep->fused serialization + launch
//  gap, invisible in 7 straight fill-censored profiles. This kernel merges both
//  passes; grid.sync() (hipLaunchCooperativeKernel — guide-endorsed for this
//  harness) replaces the boundary. Geometry: fused needs 256 blocks x 512 thr x
//  128 KB LDS = 1 block/CU on 256 CUs = exactly co-resident (the cooperative
//  requirement). Prep divides evenly: 64 X-groups/block (8/wave), 1 W-tile/block
//  (transpose scratch aliases AY). Both halves verbatim from HW-passed code
//  (R14/R20 = 105.6/107.8); the only new construct is the grid barrier.
//  Predictions: gap-hypothesis -> total 98-103; null -> 105-108 (bank stands);
//  capture-incompatible -> clean error, banked best safe.]
// ===================================================================================

__global__ __launch_bounds__(512) void fused_all(const float* __restrict__ X,
                                                 _Float16* __restrict__ XhT,
                                                 const float* __restrict__ W,
                                                 _Float16* __restrict__ WtT,
                                                 float* __restrict__ Sout,
                                                 const float* __restrict__ bias_ptr) {
    // AY: prep W-transpose scratch (float[32][33] alias), then phase-1 A-chunks
    //     [16 kt][4 rc][16 r][32 col] fp16, then Ylds[64][512].
    __shared__ __align__(16) _Float16 AY[64 * 512];        // 64 KB
    __shared__ __align__(16) _Float16 Bs[2][8 * 2048];     // 64 KB: dbuf x 8 strips

    const int tid  = threadIdx.x;
    const int lane = tid & 63;
    const int wv   = tid >> 6;        // 0..7
    const int quad = lane >> 4;       // 0..3
    const int l16  = lane & 15;
    const int l8   = lane * 8;        // fp16 offset of this lane's 16B in a chunk
    const int blk  = blockIdx.x;      // 256 blocks

    // ================= part A: prep (was its own dispatch; verbatim math) ==========
    {
        // X part: this block converts groups g = blk*64 .. blk*64+63 (8 per wave).
        const int r = lane >> 2, s = lane & 3;
#pragma unroll
        for (int i = 0; i < 8; ++i) {
            const int g  = blk * 64 + wv * 8 + i;
            const int b  = g >> 9;            // 0..31
            const int kt = (g >> 5) & 15;     // 0..15
            const int ch = g & 31;            // 0..31
            const int col = kt * 32 + ((s ^ ((r >> 1) & 3)) << 3);  // pre-swizzled
            const float* src = X + ((size_t)(b * 512 + ch * 16 + r)) * DDIM + col;
            float4 u0 = *(const float4*)src;
            float4 u1 = *(const float4*)(src + 4);
            *(f16x8*)&XhT[(size_t)g * 512 + lane * 8] = cvt8(u0, u1);
        }

        // W part: this block transposes W-tile t = blk (32x32), via LDS scratch.
        float* tileF = (float*)&AY[0];        // 32*33 floats = 4.2 KB scratch
        const int bx = blk & 15;              // e-tile
        const int by = blk >> 4;              // d-tile == kt
        if (tid < 256) {
            const int tx = tid & 31;
            const int ty = tid >> 5;          // 0..7
            for (int rr = ty; rr < 32; rr += 8)
                tileF[rr * 33 + tx] = W[(by * 32 + rr) * DDIM + bx * 32 + tx];
        }
        __syncthreads();
        if (tid < 128) {
            const int er = tid >> 2;                  // e-within 0..31
            const int sp = tid & 3;                   // physical slot
            const int rr = er & 15;                   // r within chunk
            const int sl = sp ^ ((rr >> 1) & 3);      // logical slot
            f16x8 v;
#pragma unroll
            for (int j = 0; j < 8; ++j)
                v[j] = (_Float16)tileF[(sl * 8 + j) * 33 + er];
            const int ch = bx * 2 + (er >> 4);
            *(f16x8*)&WtT[((size_t)(by * 32 + ch)) * 512 + rr * 32 + sp * 8] = v;
        }
    }

    // ---- grid-wide barrier: all XhT/WtT writes visible to all blocks ----
    __threadfence();                  // device-scope release of the prep writes
    cg::this_grid().sync();           // replaces the prep->fused dispatch boundary

    // ================= part B: fused (R14/R20 verbatim) ============================
    const int paK = (quad ^ ((l16 >> 1) & 3)) * 8;  // fragment read slot
    const int batch = blk & 31;
    const int r0    = (blk >> 5) * 64;
    const int ch0   = r0 >> 4;        // first A row-chunk (0..31, step 4)

    const _Float16* Xt = XhT + (size_t)(batch * 16) * 32 * 512;  // batch's kt-tiles

    f32x4 acc[4][4];
#pragma unroll
    for (int i = 0; i < 4; ++i)
#pragma unroll
        for (int j = 0; j < 4; ++j)
            acc[i][j] = (f32x4){0.f, 0.f, 0.f, 0.f};

    // ---- prologue: stage ALL of A (64 chunks, 8 per wave; 1KB sequential each),
    //      then B tile 0 (wave-own strip, 4 chunks). A oldest -> vmcnt(4) waits A.
#pragma unroll
    for (int c = 0; c < 8; ++c) {
        const int kt = wv * 2 + (c >> 2);         // k-tile (2 per wave)
        const int rc = c & 3;                     // row-chunk 0..3
        gl_lds16(Xt + ((size_t)(kt * 32 + ch0 + rc)) * 512 + l8,
                 &AY[(kt * 4 + rc) * 512]);
    }
#pragma unroll
    for (int t = 0; t < 4; ++t)
        gl_lds16(WtT + ((size_t)(0 * 32 + wv * 4 + t)) * 512 + l8,
                 &Bs[0][wv * 2048 + t * 512]);
    WAITVM(4);                         // A's 8 loads (oldest) complete; B0 in flight
    __builtin_amdgcn_s_barrier();      // A visible to all waves

    // ================= phase 1: Y = X_b[r0:r0+64][:] @ Wt^T  (16 iters, BK=32) =====
#pragma unroll
    for (int it = 0; it < 15; ++it) {
        const int buf = it & 1;
        const int ktn = it + 1;
#pragma unroll
        for (int t = 0; t < 4; ++t)    // stage next tile into buf^1 (wave-own strip)
            gl_lds16(WtT + ((size_t)(ktn * 32 + wv * 4 + t)) * 512 + l8,
                     &Bs[buf ^ 1][wv * 2048 + t * 512]);
        WAITVM(4);                     // tile it (oldest 4) landed; it+1 in flight
        f16x8 a[4], b[4];
#pragma unroll
        for (int mt = 0; mt < 4; ++mt)
            a[mt] = *(const f16x8*)&AY[(it * 4 + mt) * 512 + l16 * 32 + paK];
#pragma unroll
        for (int nt = 0; nt < 4; ++nt)
            b[nt] = *(const f16x8*)&Bs[buf][wv * 2048 + nt * 512 + l16 * 32 + paK];
#pragma unroll
        for (int mt = 0; mt < 4; ++mt)
#pragma unroll
            for (int nt = 0; nt < 4; ++nt)
                acc[mt][nt] = __builtin_amdgcn_mfma_f32_16x16x32_f16(
                    a[mt], b[nt], acc[mt][nt], 0, 0, 0);
    }
    {   // ---- peeled it = 15: prefetch PHASE-2 tile 0 (Xh_t, et=0) instead
        const int buf = 15 & 1;        // = 1; prefetch -> Bs[0] = phase-2 tile 0
#pragma unroll
        for (int t = 0; t < 4; ++t)
            gl_lds16(Xt + ((size_t)(0 * 32 + wv * 4 + t)) * 512 + l8,
                     &Bs[buf ^ 1][wv * 2048 + t * 512]);
        WAITVM(4);
        f16x8 a[4], b[4];
#pragma unroll
        for (int mt = 0; mt < 4; ++mt)
            a[mt] = *(const f16x8*)&AY[(15 * 4 + mt) * 512 + l16 * 32 + paK];
#pragma unroll
        for (int nt = 0; nt < 4; ++nt)
            b[nt] = *(const f16x8*)&Bs[buf][wv * 2048 + nt * 512 + l16 * 32 + paK];
#pragma unroll
        for (int mt = 0; mt < 4; ++mt)
#pragma unroll
            for (int nt = 0; nt < 4; ++nt)
                acc[mt][nt] = __builtin_amdgcn_mfma_f32_16x16x32_f16(
                    a[mt], b[nt], acc[mt][nt], 0, 0, 0);
    }

    // ---- interphase (barriers; prefetch stays in flight across both).
    __builtin_amdgcn_s_barrier();
#pragma unroll
    for (int mt = 0; mt < 4; ++mt)
#pragma unroll
        for (int nt = 0; nt < 4; ++nt)
#pragma unroll
            for (int r = 0; r < 4; ++r) {
                int i = mt * 16 + quad * 4 + r;        // Y row (0..63)
                int e = wv * 64 + nt * 16 + l16;       // Y col (0..511)
                int c = e >> 3, j = e & 7;
                AY[i * 512 + (((c ^ (i & 7)) << 3) | j)] = (_Float16)acc[mt][nt][r];
            }
    asm volatile("s_waitcnt lgkmcnt(0)" ::: "memory");
    __builtin_amdgcn_s_barrier();      // Ylds visible

    // ================= phase 2: S = Y @ X_b^T  (16 iters, BK=32, barrier-free) =====
#pragma unroll
    for (int i = 0; i < 4; ++i)
#pragma unroll
        for (int j = 0; j < 4; ++j)
            acc[i][j] = (f32x4){0.f, 0.f, 0.f, 0.f};

#pragma unroll
    for (int it = 0; it < 15; ++it) {
        const int buf = it & 1;
        const int etn = it + 1;
#pragma unroll
        for (int t = 0; t < 4; ++t)    // stage next e-tile (wave-own X strip)
            gl_lds16(Xt + ((size_t)(etn * 32 + wv * 4 + t)) * 512 + l8,
                     &Bs[buf ^ 1][wv * 2048 + t * 512]);
        WAITVM(4);
        const int pay = (((it * 4 + quad) ^ (l16 & 7)) * 8);  // Ylds swizzled col
        f16x8 a[4], b[4];
#pragma unroll
        for (int mt = 0; mt < 4; ++mt)
            a[mt] = *(const f16x8*)&AY[(mt * 16 + l16) * 512 + pay];
#pragma unroll
        for (int nt = 0; nt < 4; ++nt)
            b[nt] = *(const f16x8*)&Bs[buf][wv * 2048 + nt * 512 + l16 * 32 + paK];
#pragma unroll
        for (int mt = 0; mt < 4; ++mt)
#pragma unroll
            for (int nt = 0; nt < 4; ++nt)
                acc[mt][nt] = __builtin_amdgcn_mfma_f32_16x16x32_f16(
                    a[mt], b[nt], acc[mt][nt], 0, 0, 0);
    }
    {   // ---- peeled it = 15: drain the last own-tile
        const int buf = 15 & 1;
        WAITVM(0);
        const int pay = (((15 * 4 + quad) ^ (l16 & 7)) * 8);
        f16x8 a[4], b[4];
#pragma unroll
        for (int mt = 0; mt < 4; ++mt)
            a[mt] = *(const f16x8*)&AY[(mt * 16 + l16) * 512 + pay];
#pragma unroll
        for (int nt = 0; nt < 4; ++nt)
            b[nt] = *(const f16x8*)&Bs[buf][wv * 2048 + nt * 512 + l16 * 32 + paK];
#pragma unroll
        for (int mt = 0; mt < 4; ++mt)
#pragma unroll
            for (int nt = 0; nt < 4; ++nt)
                acc[mt][nt] = __builtin_amdgcn_mfma_f32_16x16x32_f16(
                    a[mt], b[nt], acc[mt][nt], 0, 0, 0);
    }

    // ---- epilogue: bias, zero diagonal, fp32 store
    const float bias = bias_ptr[0];
#pragma unroll
    for (int mt = 0; mt < 4; ++mt)
#pragma unroll
        for (int nt = 0; nt < 4; ++nt)
#pragma unroll
            for (int r = 0; r < 4; ++r) {
                int gi = r0 + mt * 16 + quad * 4 + r;   // row within batch
                int gj = wv * 64 + nt * 16 + l16;       // col within batch
                float v = acc[mt][nt][r] + bias;
                if (gi == gj) v = 0.f;
                Sout[((size_t)batch * NDIM + gi) * NDIM + gj] = v;
            }
}

extern "C" void kernel_launch(void* const* d_in, const int* in_sizes, int n_in,
                              void* d_out, int out_size, void* d_ws, size_t ws_size,
                              hipStream_t stream) {
    const float* X  = (const float*)d_in[0];   // (32, 512, 512) fp32
    const float* W  = (const float*)d_in[1];   // (512, 512) fp32
    const float* bp = (const float*)d_in[2];   // scalar fp32
    float* out = (float*)d_out;                // (32, 512, 512) fp32

    // workspace (fp16): XhT[8388608] | WtT[262144]
    _Float16* XhT = (_Float16*)d_ws;
    _Float16* WtT = XhT + XELEMS;

    // single cooperative dispatch: prep (64 X-groups + 1 W-tile per block) ->
    // grid.sync() -> fused (R14 structure). 256 blocks x 512 threads, 1 block/CU.
    void* args[] = { (void*)&X, (void*)&XhT, (void*)&W, (void*)&WtT,
                     (void*)&out, (void*)&bp };
    hipLaunchCooperativeKernel((const void*)fused_all, dim3(256), dim3(512),
                               args, 0, stream);
}

// Round 23
// 106.957 us; speedup vs baseline: 1.9976x; 1.9976x over previous
//
#include <hip/hip_runtime.h>
#include <stdint.h>

// Problem constants (fixed by setup_inputs): B=32, N=512, D=512
#define BATCH 32
#define NDIM 512
#define DDIM 512
#define XELEMS (BATCH * NDIM * DDIM)   // 8388608

typedef _Float16 f16x8 __attribute__((ext_vector_type(8)));
typedef float f32x4 __attribute__((ext_vector_type(4)));

__device__ __forceinline__ f16x8 cvt8(float4 u0, float4 u1) {
    f16x8 r;
    r[0] = (_Float16)u0.x; r[1] = (_Float16)u0.y;
    r[2] = (_Float16)u0.z; r[3] = (_Float16)u0.w;
    r[4] = (_Float16)u1.x; r[5] = (_Float16)u1.y;
    r[6] = (_Float16)u1.z; r[7] = (_Float16)u1.w;
    return r;
}

// --- async global -> LDS, 16 bytes per lane (global_load_lds_dwordx4) ---
__device__ __forceinline__ void gl_lds16(const _Float16* g, _Float16* l) {
    __builtin_amdgcn_global_load_lds(
        (const __attribute__((address_space(1))) unsigned int*)(g),
        (__attribute__((address_space(3))) unsigned int*)(l),
        16, 0, 0);
}

// counted vmcnt wait + scheduling fence (rule 18)
#define WAITVM(N) do { asm volatile("s_waitcnt vmcnt(" #N ")" ::: "memory"); \
                       __builtin_amdgcn_sched_barrier(0); } while (0)

// ===================================================================================
// [R22 — FINAL: R14 two-dispatch form, verbatim (measured 105.6 / 107.8 µs; session
//  baseline was 112.8). Complete experiment ledger on this fused family:
//   - tiled-swizzled global layout (R14): −4.4 µs — the only real win
//   - delete B-LDS + WAITVM machinery (R15): ±0
//   - 2 blocks/CU occupancy (R17): +5.4 regression
//   - depth-4 register prefetch (R19): ±0
//   - single cooperative dispatch w/ grid.sync (R21): +107 µs CATASTROPHIC —
//     grid.sync on 256 blocks across 8 non-coherent XCD L2s costs ~80 µs
//     (device-scope fence + rendezvous), far worse than the runtime's natural
//     inter-dispatch overlap. First uncensored fused-family counters: MfmaUtil
//     5.3 / VALUBusy 3.8 / HBM 7.9% during the merged kernel.
//  No funded hypothesis remains; converging on the best verified artifact.
//  Structure: prep builds K-tile-major pre-swizzled fp16 layouts
//    Xh_t[b][kt][ch][r][s][j] = X[b][ch*16+r][kt*32 + (s^((r>>1)&3))*8 + j]
//    Wt_t[kt][ch][r][s][j]    = W[kt*32 + (s^((r>>1)&3))*8 + j][ch*16+r]
//  so every gl_lds in fused reads lane-sequential 1KB chunks while landing the
//  byte-identical LDS image of the R5 HW-passed kernel. fused = R5 structure:
//  A staged once (64 KB AY, reused as Ylds), wave-private B strips double-buffered
//  (Bs 2x32KB), per-wave counted vmcnt(4) self-sync, 3 s_barriers total, vmcnt
//  never drained to 0 inside a loop. Fragment algebra m89-verified; vmcnt ledger
//  audited R6/R7; HW-passed rounds 8, 15, 20.]
// ===================================================================================

// ---------------- pass 0: build Xh_t (fp32->fp16, tiled+swizzled) and Wt_t ---------
__global__ __launch_bounds__(256) void prep(const float* __restrict__ X,
                                            _Float16* __restrict__ XhT,
                                            const float* __restrict__ W,
                                            _Float16* __restrict__ WtT) {
    int bid = blockIdx.x;
    if (bid < 4096) {
        // X part: 16384 groups (b,kt,ch), 4 per block; wave-contiguous 1KB writes.
        int g    = bid * 4 + (threadIdx.x >> 6);
        int lane = threadIdx.x & 63;
        int b  = g >> 9;             // 0..31
        int kt = (g >> 5) & 15;      // 0..15
        int ch = g & 31;             // 0..31
        int r = lane >> 2, s = lane & 3;
        int col = kt * 32 + ((s ^ ((r >> 1) & 3)) << 3);   // pre-swizzled source col
        const float* src = X + ((size_t)(b * 512 + ch * 16 + r)) * DDIM + col;
        float4 u0 = *(const float4*)src;
        float4 u1 = *(const float4*)(src + 4);
        *(f16x8*)&XhT[(size_t)g * 512 + lane * 8] = cvt8(u0, u1);
    } else {
        // W part: 256 tiles of 32x32; LDS transpose then tiled-swizzled 16B writes.
        __shared__ float tile[32][33];
        int t  = bid - 4096;
        int bx = t & 15;             // e-tile
        int by = t >> 4;             // d-tile == kt
        int tx = threadIdx.x & 31;
        int ty = threadIdx.x >> 5;   // 0..7
        for (int rr = ty; rr < 32; rr += 8)
            tile[rr][tx] = W[(by * 32 + rr) * DDIM + bx * 32 + tx];
        __syncthreads();
        int idx = threadIdx.x;       // threads 0..127 write one 16B slot each
        if (idx < 128) {
            int er = idx >> 2;                  // e-within 0..31
            int sp = idx & 3;                   // physical slot
            int rr = er & 15;                   // r within chunk
            int sl = sp ^ ((rr >> 1) & 3);      // logical slot
            f16x8 v;
#pragma unroll
            for (int j = 0; j < 8; ++j)
                v[j] = (_Float16)tile[sl * 8 + j][er];
            int ch = bx * 2 + (er >> 4);
            *(f16x8*)&WtT[((size_t)(by * 32 + ch)) * 512 + rr * 32 + sp * 8] = v;
        }
    }
}

// ---------------- fused: S_b = (X_b @ W) @ X_b^T + bias, diag = 0 -------------------
// Structure = R5 (3 barriers, per-wave counted vmcnt(4), B strips wave-private,
// A staged once, Ylds reuses A's LDS). Grid: 256 blocks = rslice*32 + batch
// (blk%8 = batch%8 -> one batch's 8 row-slice blocks share an XCD).
__global__ __launch_bounds__(512) void fused(const _Float16* __restrict__ XhT,
                                             const _Float16* __restrict__ WtT,
                                             float* __restrict__ Sout,
                                             const float* __restrict__ bias_ptr) {
    // AY: phase 1 = A-chunks [16 kt][4 rc][16 r][32 col] fp16; then Ylds[64][512].
    __shared__ __align__(16) _Float16 AY[64 * 512];        // 64 KB
    __shared__ __align__(16) _Float16 Bs[2][8 * 2048];     // 64 KB: dbuf x 8 strips

    const int tid  = threadIdx.x;
    const int lane = tid & 63;
    const int wv   = tid >> 6;        // 0..7
    const int quad = lane >> 4;       // 0..3
    const int l16  = lane & 15;
    const int l8   = lane * 8;        // fp16 offset of this lane's 16B in a chunk

    // fragment read slot (read side of the baked involution; rows ≡ l16 mod 16)
    const int paK = (quad ^ ((l16 >> 1) & 3)) * 8;

    const int blk   = blockIdx.x;     // 256 blocks
    const int batch = blk & 31;
    const int r0    = (blk >> 5) * 64;
    const int ch0   = r0 >> 4;        // first A row-chunk (0..31, step 4)

    const _Float16* Xt = XhT + (size_t)(batch * 16) * 32 * 512;  // batch's 16 kt-tiles

    f32x4 acc[4][4];
#pragma unroll
    for (int i = 0; i < 4; ++i)
#pragma unroll
        for (int j = 0; j < 4; ++j)
            acc[i][j] = (f32x4){0.f, 0.f, 0.f, 0.f};

    // ---- prologue: stage ALL of A (64 chunks, 8 per wave; 1KB sequential each),
    //      then B tile 0 (wave-own strip, 4 chunks). A oldest -> vmcnt(4) waits A.
#pragma unroll
    for (int c = 0; c < 8; ++c) {
        const int kt = wv * 2 + (c >> 2);         // k-tile (2 per wave)
        const int rc = c & 3;                     // row-chunk 0..3
        gl_lds16(Xt + ((size_t)(kt * 32 + ch0 + rc)) * 512 + l8,
                 &AY[(kt * 4 + rc) * 512]);
    }
#pragma unroll
    for (int t = 0; t < 4; ++t)
        gl_lds16(WtT + ((size_t)(0 * 32 + wv * 4 + t)) * 512 + l8,
                 &Bs[0][wv * 2048 + t * 512]);
    WAITVM(4);                         // A's 8 loads (oldest) complete; B0 in flight
    __builtin_amdgcn_s_barrier();      // A visible to all waves

    // ================= phase 1: Y = X_b[r0:r0+64][:] @ Wt^T  (16 iters, BK=32) =====
#pragma unroll
    for (int it = 0; it < 15; ++it) {
        const int buf = it & 1;
        const int ktn = it + 1;
#pragma unroll
        for (int t = 0; t < 4; ++t)    // stage next tile into buf^1 (wave-own strip)
            gl_lds16(WtT + ((size_t)(ktn * 32 + wv * 4 + t)) * 512 + l8,
                     &Bs[buf ^ 1][wv * 2048 + t * 512]);
        WAITVM(4);                     // tile it (oldest 4) landed; it+1 in flight
        f16x8 a[4], b[4];
#pragma unroll
        for (int mt = 0; mt < 4; ++mt)
            a[mt] = *(const f16x8*)&AY[(it * 4 + mt) * 512 + l16 * 32 + paK];
#pragma unroll
        for (int nt = 0; nt < 4; ++nt)
            b[nt] = *(const f16x8*)&Bs[buf][wv * 2048 + nt * 512 + l16 * 32 + paK];
#pragma unroll
        for (int mt = 0; mt < 4; ++mt)
#pragma unroll
            for (int nt = 0; nt < 4; ++nt)
                acc[mt][nt] = __builtin_amdgcn_mfma_f32_16x16x32_f16(
                    a[mt], b[nt], acc[mt][nt], 0, 0, 0);
    }
    {   // ---- peeled it = 15: prefetch PHASE-2 tile 0 (Xh_t, et=0) instead
        const int buf = 15 & 1;        // = 1; prefetch -> Bs[0] = phase-2 tile 0
#pragma unroll
        for (int t = 0; t < 4; ++t)
            gl_lds16(Xt + ((size_t)(0 * 32 + wv * 4 + t)) * 512 + l8,
                     &Bs[buf ^ 1][wv * 2048 + t * 512]);
        WAITVM(4);
        f16x8 a[4], b[4];
#pragma unroll
        for (int mt = 0; mt < 4; ++mt)
            a[mt] = *(const f16x8*)&AY[(15 * 4 + mt) * 512 + l16 * 32 + paK];
#pragma unroll
        for (int nt = 0; nt < 4; ++nt)
            b[nt] = *(const f16x8*)&Bs[buf][wv * 2048 + nt * 512 + l16 * 32 + paK];
#pragma unroll
        for (int mt = 0; mt < 4; ++mt)
#pragma unroll
            for (int nt = 0; nt < 4; ++nt)
                acc[mt][nt] = __builtin_amdgcn_mfma_f32_16x16x32_f16(
                    a[mt], b[nt], acc[mt][nt], 0, 0, 0);
    }

    // ---- interphase (barriers #2, #3; prefetch stays in flight across both).
    __builtin_amdgcn_s_barrier();
#pragma unroll
    for (int mt = 0; mt < 4; ++mt)
#pragma unroll
        for (int nt = 0; nt < 4; ++nt)
#pragma unroll
            for (int r = 0; r < 4; ++r) {
                int i = mt * 16 + quad * 4 + r;        // Y row (0..63)
                int e = wv * 64 + nt * 16 + l16;       // Y col (0..511)
                int c = e >> 3, j = e & 7;
                AY[i * 512 + (((c ^ (i & 7)) << 3) | j)] = (_Float16)acc[mt][nt][r];
            }
    asm volatile("s_waitcnt lgkmcnt(0)" ::: "memory");
    __builtin_amdgcn_s_barrier();      // Ylds visible

    // ================= phase 2: S = Y @ X_b^T  (16 iters, BK=32, barrier-free) =====
#pragma unroll
    for (int i = 0; i < 4; ++i)
#pragma unroll
        for (int j = 0; j < 4; ++j)
            acc[i][j] = (f32x4){0.f, 0.f, 0.f, 0.f};

#pragma unroll
    for (int it = 0; it < 15; ++it) {
        const int buf = it & 1;
        const int etn = it + 1;
#pragma unroll
        for (int t = 0; t < 4; ++t)    // stage next e-tile (wave-own X strip)
            gl_lds16(Xt + ((size_t)(etn * 32 + wv * 4 + t)) * 512 + l8,
                     &Bs[buf ^ 1][wv * 2048 + t * 512]);
        WAITVM(4);
        const int pay = (((it * 4 + quad) ^ (l16 & 7)) * 8);  // Ylds swizzled col
        f16x8 a[4], b[4];
#pragma unroll
        for (int mt = 0; mt < 4; ++mt)
            a[mt] = *(const f16x8*)&AY[(mt * 16 + l16) * 512 + pay];
#pragma unroll
        for (int nt = 0; nt < 4; ++nt)
            b[nt] = *(const f16x8*)&Bs[buf][wv * 2048 + nt * 512 + l16 * 32 + paK];
#pragma unroll
        for (int mt = 0; mt < 4; ++mt)
#pragma unroll
            for (int nt = 0; nt < 4; ++nt)
                acc[mt][nt] = __builtin_amdgcn_mfma_f32_16x16x32_f16(
                    a[mt], b[nt], acc[mt][nt], 0, 0, 0);
    }
    {   // ---- peeled it = 15: drain the last own-tile
        const int buf = 15 & 1;
        WAITVM(0);
        const int pay = (((15 * 4 + quad) ^ (l16 & 7)) * 8);
        f16x8 a[4], b[4];
#pragma unroll
        for (int mt = 0; mt < 4; ++mt)
            a[mt] = *(const f16x8*)&AY[(mt * 16 + l16) * 512 + pay];
#pragma unroll
        for (int nt = 0; nt < 4; ++nt)
            b[nt] = *(const f16x8*)&Bs[buf][wv * 2048 + nt * 512 + l16 * 32 + paK];
#pragma unroll
        for (int mt = 0; mt < 4; ++mt)
#pragma unroll
            for (int nt = 0; nt < 4; ++nt)
                acc[mt][nt] = __builtin_amdgcn_mfma_f32_16x16x32_f16(
                    a[mt], b[nt], acc[mt][nt], 0, 0, 0);
    }

    // ---- epilogue: bias, zero diagonal, fp32 store
    const float bias = bias_ptr[0];
#pragma unroll
    for (int mt = 0; mt < 4; ++mt)
#pragma unroll
        for (int nt = 0; nt < 4; ++nt)
#pragma unroll
            for (int r = 0; r < 4; ++r) {
                int gi = r0 + mt * 16 + quad * 4 + r;   // row within batch
                int gj = wv * 64 + nt * 16 + l16;       // col within batch
                float v = acc[mt][nt][r] + bias;
                if (gi == gj) v = 0.f;
                Sout[((size_t)batch * NDIM + gi) * NDIM + gj] = v;
            }
}

extern "C" void kernel_launch(void* const* d_in, const int* in_sizes, int n_in,
                              void* d_out, int out_size, void* d_ws, size_t ws_size,
                              hipStream_t stream) {
    const float* X  = (const float*)d_in[0];   // (32, 512, 512) fp32
    const float* W  = (const float*)d_in[1];   // (512, 512) fp32
    const float* bp = (const float*)d_in[2];   // scalar fp32
    float* out = (float*)d_out;                // (32, 512, 512) fp32

    // workspace (fp16): XhT[8388608] | WtT[262144]
    _Float16* XhT = (_Float16*)d_ws;
    _Float16* WtT = XhT + XELEMS;

    // pass 0: tiled+swizzled fp16 layouts (4096 X-blocks + 256 W-blocks)
    prep<<<4096 + 256, 256, 0, stream>>>(X, XhT, W, WtT);

    // fused: R5 structure, staging reads lane-sequential 1KB chunks
    fused<<<256, 512, 0, stream>>>(XhT, WtT, out, bp);

    (void)in_sizes; (void)n_in; (void)out_size; (void)ws_size;
}